// Round 8
// baseline (122.289 us; speedup 1.0000x reference)
//
#include <hip/hip_runtime.h>
#include <math.h>

#define B_   64
#define L_   500
#define F_   256
#define H_   4
#define DK   64

typedef unsigned short u16;
typedef unsigned int   u32;
typedef __attribute__((ext_vector_type(8))) short short8;
typedef __attribute__((ext_vector_type(4))) float f32x4;

static __device__ __forceinline__ u16 f2bf(float f) {
    u32 u = __float_as_uint(f);
    u32 r = (u + 0x7FFFu + ((u >> 16) & 1u)) >> 16;
    return (u16)r;
}
// round-half-up bf16 (2 ops); differs from RNE only on exact ties
static __device__ __forceinline__ u16 f2bf_up(float f) {
    return (u16)((__float_as_uint(f) + 0x8000u) >> 16);
}

typedef __attribute__((address_space(3))) u32 lds32;
typedef const __attribute__((address_space(1))) u32 gbl32;
// async global->LDS DMA, 16 B/lane, LDS dest = uniform base + lane*16
static __device__ __forceinline__ void gload_lds16(const u16* g, u16* l) {
    __builtin_amdgcn_global_load_lds((gbl32*)g, (lds32*)l, 16, 0, 0);
}

// ---------------------------------------------------------------------------
// Prep: bf16 transposed weights + padded b2 + pad-zeroing of ws regions.
//  wqT/wvT/fcwT [256][256] ([n][k]); w1T[64][64]
//  w2sw: chunk-tiled + XOR-swizzled: [cc=8][row=64][k=64],
//        w2sw[cc][row][k] = w2[k ^ ((row&7)<<3)][cc*64+row]  (col>=500 -> 0)
//  b2p[512] float (tail -1e30); zero qh_bf pad rows + vhT swizzled pad slots.
// ---------------------------------------------------------------------------
__global__ __launch_bounds__(256) void prep_kernel(
    const float* __restrict__ wq, const float* __restrict__ wv,
    const float* __restrict__ fcw, const float* __restrict__ w1,
    const float* __restrict__ w2, const float* __restrict__ b2,
    u16* __restrict__ wqT, u16* __restrict__ wvT, u16* __restrict__ fcwT,
    u16* __restrict__ w1T, u16* __restrict__ w2sw,
    u16* __restrict__ qh_bf, u16* __restrict__ vhT, float* __restrict__ b2p)
{
    int t = blockIdx.x * 256 + threadIdx.x;
    int stride = gridDim.x * 256;                 // 16384
    for (int i = t; i < 256 * 256; i += stride) {
        int n = i >> 8, k = i & 255;
        wqT[i]  = f2bf(wq[k * 256 + n]);
        wvT[i]  = f2bf(wv[k * 256 + n]);
        fcwT[i] = f2bf(fcw[k * 256 + n]);
    }
    for (int i = t; i < 64 * 64; i += stride) {
        int n = i >> 6, k = i & 63;
        w1T[i] = f2bf(w1[k * 64 + n]);
    }
    // w2 chunk-tiled + swizzled
    for (int i = t; i < 512 * 64; i += stride) {
        int cc  = i >> 12;            // chunk of 64 cols
        int row = (i >> 6) & 63;      // col within chunk
        int kc  = i & 63;
        int n   = cc * 64 + row;      // global output col
        int kl  = kc ^ ((row & 7) << 3);
        w2sw[i] = f2bf(n < 500 ? w2[kl * 500 + n] : 0.f);
    }
    // padded bias (tail -> exp() == 0)
    for (int i = t; i < 512; i += stride)
        b2p[i] = (i < 500) ? b2[i] : -1e30f;
    // zero qh_bf pad rows read by attn (rows >= 128000); b2p lives at 8195072+
    for (int i = t; i < 3072; i += stride)
        qh_bf[8192000 + i] = 0;
    // zero vhT swizzled pad slots: chunk 7, k 52..63 for every (bh, d)
    for (int i = t; i < 196608; i += stride) {
        int bh = i / 768;
        int r  = i - bh * 768;
        int d  = r / 12;
        int kk = 52 + (r - d * 12);
        vhT[((size_t)((bh * 8 + 7) * 64 + d)) * 64 + (kk ^ ((d & 7) << 3))] = 0;
    }
}

// ---------------------------------------------------------------------------
// Kernel 1: head projections, bf16 MFMA.
// grid (500, 2), block 512 = 8 waves in 2x4; block tile 64 rows x 256 cols.
// which=0: qh_bf [bh][500][64]
// which=1: vhT chunk-tiled+swizzled [bh][cc=8][d=64][k=64],
//          vhT[bh][cc][d][k ^ ((d&7)<<3)] = v_head[bh][d][cc*64+k]
// ---------------------------------------------------------------------------
__global__ __launch_bounds__(512) void proj_kernel(
    const float* __restrict__ q, const float* __restrict__ v,
    const u16* __restrict__ wqT, const u16* __restrict__ wvT,
    u16* __restrict__ qh_bf, u16* __restrict__ vhT)
{
    const int which = blockIdx.y;
    const float* __restrict__ x = which ? v : q;
    const u16*   __restrict__ wT = which ? wvT : wqT;

    __shared__ u16 Xs[64][72];    // [m][k], pad 144 B
    __shared__ u16 Ws[256][72];   // [n][k], pad 144 B

    const int tid  = threadIdx.x;
    const int wvid = tid >> 6, ln = tid & 63;
    const int n16  = ln & 15, quad = ln >> 4;
    const int wr   = wvid >> 2, wc = wvid & 3;   // 2 x 4
    const int row0 = blockIdx.x * 64;

    f32x4 acc[2][4];
    #pragma unroll
    for (int mt = 0; mt < 2; mt++)
        #pragma unroll
        for (int nt = 0; nt < 4; nt++) acc[mt][nt] = (f32x4){0.f, 0.f, 0.f, 0.f};

    for (int kc = 0; kc < 256; kc += 64) {
        // stage X (fp32 -> bf16): 64 x 64
        #pragma unroll
        for (int j = 0; j < 2; j++) {
            int idx = tid + 512 * j;
            int m = idx >> 4, k4 = idx & 15;
            float4 a = *(const float4*)&x[(size_t)(row0 + m) * 256 + kc + k4 * 4];
            __align__(8) u16 t4[4] = {f2bf(a.x), f2bf(a.y), f2bf(a.z), f2bf(a.w)};
            *(uint2*)&Xs[m][k4 * 4] = *(const uint2*)t4;
        }
        // stage W^T: 256 x 64 bf16
        #pragma unroll
        for (int j = 0; j < 4; j++) {
            int idx = tid + 512 * j;
            int n = idx >> 3, k8 = idx & 7;
            *(uint4*)&Ws[n][k8 * 8] = *(const uint4*)&wT[n * 256 + kc + k8 * 8];
        }
        __syncthreads();
        #pragma unroll
        for (int ks = 0; ks < 2; ks++) {
            short8 af[2], bfr[4];
            #pragma unroll
            for (int mt = 0; mt < 2; mt++)
                af[mt] = *(const short8*)&Xs[wr * 32 + mt * 16 + n16][ks * 32 + quad * 8];
            #pragma unroll
            for (int nt = 0; nt < 4; nt++)
                bfr[nt] = *(const short8*)&Ws[wc * 64 + nt * 16 + n16][ks * 32 + quad * 8];
            #pragma unroll
            for (int mt = 0; mt < 2; mt++)
                #pragma unroll
                for (int nt = 0; nt < 4; nt++)
                    acc[mt][nt] = __builtin_amdgcn_mfma_f32_16x16x32_bf16(
                        af[mt], bfr[nt], acc[mt][nt], 0, 0, 0);
        }
        __syncthreads();
    }

    // h = wc (64-col groups), d = nt*16 + n16
    if (which == 0) {
        #pragma unroll
        for (int mt = 0; mt < 2; mt++) {
            int m0 = row0 + wr * 32 + mt * 16 + quad * 4;   // mult of 4
            int b  = m0 / 500;
            int l0 = m0 - 500 * b;                           // group never straddles b
            #pragma unroll
            for (int nt = 0; nt < 4; nt++) {
                int d = nt * 16 + n16;
                u16* dst = qh_bf + ((size_t)((b * 4 + wc) * 500 + l0)) * 64 + d;
                #pragma unroll
                for (int i = 0; i < 4; i++)
                    dst[(size_t)i * 64] = f2bf(acc[mt][nt][i]);
            }
        }
    } else {
        #pragma unroll
        for (int mt = 0; mt < 2; mt++) {
            int m0 = row0 + wr * 32 + mt * 16 + quad * 4;
            int b  = m0 / 500;
            int l0 = m0 - 500 * b;                           // 4-aligned
            int cc = l0 >> 6, kk = l0 & 63;
            #pragma unroll
            for (int nt = 0; nt < 4; nt++) {
                int d = nt * 16 + n16;
                __align__(8) u16 t4[4];
                #pragma unroll
                for (int i = 0; i < 4; i++) t4[i] = f2bf(acc[mt][nt][i]);
                size_t base = ((size_t)(((b * 4 + wc) * 8 + cc) * 64 + d)) * 64;
                *(uint2*)&vhT[base + (kk ^ ((d & 7) << 3))] = *(const uint2*)t4;
            }
        }
    }
}

// ---------------------------------------------------------------------------
// Kernel 2: dense-synthesizer attention — w2-resident, V-streamed, 16 waves.
// grid (256) = 1 block/bh/CU; block 1024 = 16 waves x 2 row-groups x 16 rows.
// LDS: w2 resident (64KB) + V double-buffered (16KB) + scratch (36KB) + b2
// = 120.8KB -> 1 block/CU, 4 waves/SIMD.
// amdgpu_waves_per_eu(4,4): pins occupancy to exactly 4 waves/EU -> the
// register allocator gets the full 512/4 = 128-VGPR budget and has no
// incentive to squeeze to 64.  (R6's bare launch_bounds and R7's min-only
// second arg both let the heuristic target 8 waves/EU -> 64 VGPR -> 218MB
// scratch spill.)
// ---------------------------------------------------------------------------
__global__ __launch_bounds__(1024)
__attribute__((amdgpu_waves_per_eu(4, 4)))
void attn_kernel(
    const u16* __restrict__ qh, const u16* __restrict__ vhT,
    const u16* __restrict__ w1T, const float* __restrict__ b1,
    const u16* __restrict__ w2sw, const float* __restrict__ b2p,
    u16* __restrict__ ctx)
{
    __shared__ __align__(16) u16 w2all[32768];     // [cc][row][k^swz], 64KB
    __shared__ __align__(16) u16 v_s[2][4096];     // [buf][d*64 + k^swz], 16KB
    __shared__ __align__(16) float b2s[512];
    __shared__ __align__(16) u16 scr[16][16][72];  // per-wave s / P scratch

    const int tid  = threadIdx.x;
    const int wv   = tid >> 6;       // 0..15
    const int ln   = tid & 63;
    const int n16  = ln & 15;
    const int quad = ln >> 4;
    const int bh   = blockIdx.x;

    const u16* vg = vhT + (size_t)bh * 32768;

    // ---- (a) Phase-A input loads FIRST (oldest in vmcnt queue) ----
    short8 a0[2], a1[2];
    #pragma unroll
    for (int rg = 0; rg < 2; rg++) {
        const u16* qbase = qh + ((size_t)(bh * 500 + rg * 256 + wv * 16 + n16)) * 64;
        a0[rg] = *(const short8*)(qbase + quad * 8);
        a1[rg] = *(const short8*)(qbase + 32 + quad * 8);
    }
    short8 w1b0[4], w1b1[4];
    float  b1v[4];
    #pragma unroll
    for (int nt = 0; nt < 4; nt++) {
        const u16* wb = w1T + (nt * 16 + n16) * 64;
        w1b0[nt] = *(const short8*)(wb + quad * 8);
        w1b1[nt] = *(const short8*)(wb + 32 + quad * 8);
        b1v[nt]  = b1[nt * 16 + n16];
    }
    __builtin_amdgcn_sched_barrier(0);

    // ---- (b) one-shot staging: all of w2 (4 DMA/wave), v[0], b2 ----
    {
        int base = wv * 2048;           // 2048 u16 per wave (4 KB)
        #pragma unroll
        for (int j = 0; j < 4; j++)
            gload_lds16(w2sw + base + j * 512 + ln * 8, &w2all[base + j * 512]);
        if (wv < 8)
            gload_lds16(vg + wv * 512 + ln * 8, &v_s[0][wv * 512]);
        if (wv >= 14)
            gload_lds16((const u16*)b2p + (wv - 14) * 512 + ln * 8,
                        (u16*)&b2s[(wv - 14) * 256]);
    }
    __builtin_amdgcn_sched_barrier(0);

    // ---- (c) Phase A: s = relu(qh @ w1 + b1) for 2 row-groups ----
    short8 sa0[2], sa1[2];
    #pragma unroll
    for (int rg = 0; rg < 2; rg++) {
        #pragma unroll
        for (int nt = 0; nt < 4; nt++) {
            float bias = b1v[nt];
            f32x4 c = {bias, bias, bias, bias};
            c = __builtin_amdgcn_mfma_f32_16x16x32_bf16(a0[rg], w1b0[nt], c, 0, 0, 0);
            c = __builtin_amdgcn_mfma_f32_16x16x32_bf16(a1[rg], w1b1[nt], c, 0, 0, 0);
            int col = nt * 16 + n16;
            #pragma unroll
            for (int i = 0; i < 4; i++)
                scr[wv][quad * 4 + i][col] = f2bf(fmaxf(c[i], 0.f));
        }
        sa0[rg] = *(const short8*)&scr[wv][n16][quad * 8];
        sa1[rg] = *(const short8*)&scr[wv][n16][32 + quad * 8];
    }

    f32x4 oacc[2][4];
    #pragma unroll
    for (int rg = 0; rg < 2; rg++)
        #pragma unroll
        for (int nt = 0; nt < 4; nt++) oacc[rg][nt] = (f32x4){0.f, 0.f, 0.f, 0.f};
    float sm[2][4] = {{0.f, 0.f, 0.f, 0.f}, {0.f, 0.f, 0.f, 0.f}};

    __syncthreads();   // staging complete (w2all, v[0], b2s ready)

    // ---- (d) main: 8 chunks x 2 row-groups; barrier only for V dbuf ----
    #pragma unroll 2
    for (int cc = 0; cc < 8; cc++) {
        if (cc < 7 && wv < 8)   // stage next V chunk into the other buffer
            gload_lds16(vg + (cc + 1) * 4096 + wv * 512 + ln * 8,
                        &v_s[(cc + 1) & 1][wv * 512]);
        const u16* vbuf = &v_s[cc & 1][0];

        #pragma unroll
        for (int rg = 0; rg < 2; rg++) {
            // logits: 4 col-tiles of 16 (w2 resident in LDS)
            f32x4 c8[4];
            #pragma unroll
            for (int t = 0; t < 4; t++) {
                int r  = t * 16 + n16;
                int sw = (r & 7) << 3;
                const u16* wb = &w2all[cc * 4096 + r * 64];
                short8 b0  = *(const short8*)&wb[(quad * 8) ^ sw];
                short8 b1f = *(const short8*)&wb[(32 + quad * 8) ^ sw];
                float bias = b2s[cc * 64 + r];
                f32x4 c = {bias, bias, bias, bias};
                c = __builtin_amdgcn_mfma_f32_16x16x32_bf16(sa0[rg], b0, c, 0, 0, 0);
                c = __builtin_amdgcn_mfma_f32_16x16x32_bf16(sa1[rg], b1f, c, 0, 0, 0);
                c8[t] = c;
            }
            // exp (no max-pass) + running sum; P -> bf16 (half-up) -> scratch
            #pragma unroll
            for (int t = 0; t < 4; t++) {
                int col = t * 16 + n16;
                #pragma unroll
                for (int i = 0; i < 4; i++) {
                    float e = __expf(c8[t][i]);
                    sm[rg][i] += e;
                    scr[wv][quad * 4 + i][col] = f2bf_up(e);
                }
            }
            // PV on this chunk
            #pragma unroll
            for (int ks = 0; ks < 2; ks++) {
                short8 pa = *(const short8*)&scr[wv][n16][ks * 32 + quad * 8];
                #pragma unroll
                for (int nt = 0; nt < 4; nt++) {
                    int d   = nt * 16 + n16;
                    int swd = (d & 7) << 3;
                    short8 vb2 = *(const short8*)&vbuf[d * 64 +
                                                       ((ks * 32 + quad * 8) ^ swd)];
                    oacc[rg][nt] = __builtin_amdgcn_mfma_f32_16x16x32_bf16(
                        pa, vb2, oacc[rg][nt], 0, 0, 0);
                }
            }
        }
        __syncthreads();   // next V staged; all waves done with current buffer
    }

    // ---- epilogue: row-sum reduce, scaled bf16 store ----
    const int b = bh >> 2, h = bh & 3;
    #pragma unroll
    for (int rg = 0; rg < 2; rg++) {
        #pragma unroll
        for (int off = 1; off < 16; off <<= 1) {
            #pragma unroll
            for (int i = 0; i < 4; i++) sm[rg][i] += __shfl_xor(sm[rg][i], off);
        }
        #pragma unroll
        for (int i = 0; i < 4; i++) {
            int lrow = rg * 256 + wv * 16 + quad * 4 + i;
            if (lrow < 500) {
                float s = 1.f / sm[rg][i];
                u16* dst = &ctx[((size_t)(b * 500 + lrow)) * 256 + h * 64];
                #pragma unroll
                for (int nt = 0; nt < 4; nt++)
                    dst[nt * 16 + n16] = f2bf(oacc[rg][nt][i] * s);
            }
        }
    }
}

// ---------------------------------------------------------------------------
// Kernel 3: out = LayerNorm(ctx @ fc_w + q), bf16 MFMA + fused LN epilogue.
// grid (500), block 512 = 8 waves in 2x4; block tile 64 rows x 256 cols.
// ---------------------------------------------------------------------------
__global__ __launch_bounds__(512) void final_kernel(
    const u16* __restrict__ ctx, const u16* __restrict__ fcwT,
    const float* __restrict__ qres, const float* __restrict__ g,
    const float* __restrict__ bta, float* __restrict__ out)
{
    __shared__ u16 Xs[64][72];
    __shared__ u16 Ws[256][72];
    __shared__ float red[4][2][64];   // [wc][s1|s2][row]
    __shared__ float murs[2][64];     // [mu|rs][row]

    const int tid  = threadIdx.x;
    const int wvid = tid >> 6, ln = tid & 63;
    const int n16  = ln & 15, quad = ln >> 4;
    const int wr   = wvid >> 2, wc = wvid & 3;   // 2 x 4
    const int row0 = blockIdx.x * 64;

    f32x4 acc[2][4];
    #pragma unroll
    for (int mt = 0; mt < 2; mt++)
        #pragma unroll
        for (int nt = 0; nt < 4; nt++) acc[mt][nt] = (f32x4){0.f, 0.f, 0.f, 0.f};

    for (int kc = 0; kc < 256; kc += 64) {
        // stage X: 64 x 64 bf16
        {
            int idx = tid;
            int m = idx >> 3, k8 = idx & 7;
            *(uint4*)&Xs[m][k8 * 8] =
                *(const uint4*)&ctx[(size_t)(row0 + m) * 256 + kc + k8 * 8];
        }
        // stage W^T: 256 x 64 bf16
        #pragma unroll
        for (int j = 0; j < 4; j++) {
            int idx = tid + 512 * j;
            int n = idx >> 3, k8 = idx & 7;
            *(uint4*)&Ws[n][k8 * 8] = *(const uint4*)&fcwT[n * 256 + kc + k8 * 8];
        }
        __syncthreads();
        #pragma unroll
        for (int ks = 0; ks < 2; ks++) {
            short8 af[2], bfr[4];
            #pragma unroll
            for (int mt = 0; mt < 2; mt++)
                af[mt] = *(const short8*)&Xs[wr * 32 + mt * 16 + n16][ks * 32 + quad * 8];
            #pragma unroll
            for (int nt = 0; nt < 4; nt++)
                bfr[nt] = *(const short8*)&Ws[wc * 64 + nt * 16 + n16][ks * 32 + quad * 8];
            #pragma unroll
            for (int mt = 0; mt < 2; mt++)
                #pragma unroll
                for (int nt = 0; nt < 4; nt++)
                    acc[mt][nt] = __builtin_amdgcn_mfma_f32_16x16x32_bf16(
                        af[mt], bfr[nt], acc[mt][nt], 0, 0, 0);
        }
        __syncthreads();
    }

    // residual add
    #pragma unroll
    for (int mt = 0; mt < 2; mt++) {
        int m0 = row0 + wr * 32 + mt * 16 + quad * 4;
        #pragma unroll
        for (int i = 0; i < 4; i++) {
            const float* rp = &qres[(size_t)(m0 + i) * 256 + wc * 64 + n16];
            #pragma unroll
            for (int nt = 0; nt < 4; nt++)
                acc[mt][nt][i] += rp[nt * 16];
        }
    }
    // per-row partial sums -> LDS
    #pragma unroll
    for (int mt = 0; mt < 2; mt++) {
        #pragma unroll
        for (int i = 0; i < 4; i++) {
            float s1 = 0.f, s2 = 0.f;
            #pragma unroll
            for (int nt = 0; nt < 4; nt++) {
                float vv = acc[mt][nt][i];
                s1 += vv; s2 += vv * vv;
            }
            #pragma unroll
            for (int off = 1; off < 16; off <<= 1) {
                s1 += __shfl_xor(s1, off);
                s2 += __shfl_xor(s2, off);
            }
            if (n16 == 0) {
                int r = wr * 32 + mt * 16 + quad * 4 + i;
                red[wc][0][r] = s1;
                red[wc][1][r] = s2;
            }
        }
    }
    __syncthreads();
    if (tid < 64) {
        float S1 = red[0][0][tid] + red[1][0][tid] + red[2][0][tid] + red[3][0][tid];
        float S2 = red[0][1][tid] + red[1][1][tid] + red[2][1][tid] + red[3][1][tid];
        float mu  = S1 * 0.00390625f;
        float var = S2 * 0.00390625f - mu * mu;
        murs[0][tid] = mu;
        murs[1][tid] = rsqrtf(var + 1e-6f);
    }
    __syncthreads();

    float gv[4], bv[4];
    #pragma unroll
    for (int nt = 0; nt < 4; nt++) {
        int col = wc * 64 + nt * 16 + n16;
        gv[nt] = g[col];
        bv[nt] = bta[col];
    }
    #pragma unroll
    for (int mt = 0; mt < 2; mt++) {
        int rb = wr * 32 + mt * 16 + quad * 4;
        #pragma unroll
        for (int i = 0; i < 4; i++) {
            float mu = murs[0][rb + i];
            float rs = murs[1][rb + i];
            float* op = &out[(size_t)(row0 + rb + i) * 256 + wc * 64 + n16];
            #pragma unroll
            for (int nt = 0; nt < 4; nt++)
                op[nt * 16] = (acc[mt][nt][i] - mu) * rs * gv[nt] + bv[nt];
        }
    }
}

// ---------------------------------------------------------------------------
extern "C" void kernel_launch(void* const* d_in, const int* in_sizes, int n_in,
                              void* d_out, int out_size, void* d_ws, size_t ws_size,
                              hipStream_t stream)
{
    const float* q   = (const float*)d_in[0];
    const float* v   = (const float*)d_in[2];
    const float* wqs = (const float*)d_in[3];
    const float* wvs = (const float*)d_in[4];
    const float* w1  = (const float*)d_in[5];
    const float* b1  = (const float*)d_in[6];
    const float* w2  = (const float*)d_in[7];
    const float* b2  = (const float*)d_in[8];
    const float* fcw = (const float*)d_in[9];
    const float* lng = (const float*)d_in[10];
    const float* lnb = (const float*)d_in[11];
    float* out = (float*)d_out;

    u16* qh_bf = (u16*)d_ws;            // 8,200,192 (rows >=500*256 are pad)
    u16* vhT   = qh_bf + 8200192;       // 8,388,608 (chunk-tiled + swizzled)
    u16* w1T   = vhT + 8388608;         // 4,096
    u16* w2sw  = w1T + 4096;            // 32,768 (chunk-tiled + swizzled)
    u16* wqT   = w2sw + 32768;          // 65,536
    u16* wvT   = wqT + 65536;           // 65,536
    u16* fcwT  = wvT + 65536;           // 65,536
    u16* ctx   = fcwT + 65536;          // 8,192,000
    float* b2p = (float*)(qh_bf + 8195072);  // 512 floats inside qh_bf tail pad

    prep_kernel <<<dim3(64),     256, 0, stream>>>(wqs, wvs, fcw, w1, w2, b2,
                                                   wqT, wvT, fcwT, w1T, w2sw,
                                                   qh_bf, vhT, b2p);
    proj_kernel <<<dim3(500, 2), 512, 0, stream>>>(q, v, wqT, wvT, qh_bf, vhT);
    attn_kernel <<<dim3(256),   1024, 0, stream>>>(qh_bf, vhT, w1T, b1, w2sw, b2p, ctx);
    final_kernel<<<dim3(500),    512, 0, stream>>>(ctx, fcwT, q, lng, lnb, out);
}

// Round 9
// 92.807 us; speedup vs baseline: 1.3177x; 1.3177x over previous
//
#include <hip/hip_runtime.h>
#include <math.h>

#define B_   64
#define L_   500
#define F_   256
#define H_   4
#define DK   64

typedef unsigned short u16;
typedef unsigned int   u32;
typedef __attribute__((ext_vector_type(8))) short short8;
typedef __attribute__((ext_vector_type(4))) float f32x4;

static __device__ __forceinline__ u16 f2bf(float f) {
    u32 u = __float_as_uint(f);
    u32 r = (u + 0x7FFFu + ((u >> 16) & 1u)) >> 16;
    return (u16)r;
}
// round-half-up bf16 (2 ops); differs from RNE only on exact ties
static __device__ __forceinline__ u16 f2bf_up(float f) {
    return (u16)((__float_as_uint(f) + 0x8000u) >> 16);
}

typedef __attribute__((address_space(3))) u32 lds32;
typedef const __attribute__((address_space(1))) u32 gbl32;
// async global->LDS DMA, 16 B/lane, LDS dest = uniform base + lane*16
static __device__ __forceinline__ void gload_lds16(const u16* g, u16* l) {
    __builtin_amdgcn_global_load_lds((gbl32*)g, (lds32*)l, 16, 0, 0);
}

// ---------------------------------------------------------------------------
// Prep: bf16 transposed weights + padded b2 + pad-zeroing of ws regions.
//  wqT/wvT/fcwT [256][256] ([n][k]); w1T[64][64]
//  w2sw: chunk-tiled + XOR-swizzled: [cc=8][row=64][k=64],
//        w2sw[cc][row][k] = w2[k ^ ((row&7)<<3)][cc*64+row]  (col>=500 -> 0)
//  b2p[512] float (tail -1e30); zero qh_bf pad rows + vhT swizzled pad slots.
// ---------------------------------------------------------------------------
__global__ __launch_bounds__(256) void prep_kernel(
    const float* __restrict__ wq, const float* __restrict__ wv,
    const float* __restrict__ fcw, const float* __restrict__ w1,
    const float* __restrict__ w2, const float* __restrict__ b2,
    u16* __restrict__ wqT, u16* __restrict__ wvT, u16* __restrict__ fcwT,
    u16* __restrict__ w1T, u16* __restrict__ w2sw,
    u16* __restrict__ qh_bf, u16* __restrict__ vhT, float* __restrict__ b2p)
{
    int t = blockIdx.x * 256 + threadIdx.x;
    int stride = gridDim.x * 256;                 // 16384
    for (int i = t; i < 256 * 256; i += stride) {
        int n = i >> 8, k = i & 255;
        wqT[i]  = f2bf(wq[k * 256 + n]);
        wvT[i]  = f2bf(wv[k * 256 + n]);
        fcwT[i] = f2bf(fcw[k * 256 + n]);
    }
    for (int i = t; i < 64 * 64; i += stride) {
        int n = i >> 6, k = i & 63;
        w1T[i] = f2bf(w1[k * 64 + n]);
    }
    // w2 chunk-tiled + swizzled
    for (int i = t; i < 512 * 64; i += stride) {
        int cc  = i >> 12;            // chunk of 64 cols
        int row = (i >> 6) & 63;      // col within chunk
        int kc  = i & 63;
        int n   = cc * 64 + row;      // global output col
        int kl  = kc ^ ((row & 7) << 3);
        w2sw[i] = f2bf(n < 500 ? w2[kl * 500 + n] : 0.f);
    }
    // padded bias (tail -> exp() == 0)
    for (int i = t; i < 512; i += stride)
        b2p[i] = (i < 500) ? b2[i] : -1e30f;
    // zero qh_bf pad rows read by attn (rows >= 128000); b2p lives at 8195072+
    for (int i = t; i < 3072; i += stride)
        qh_bf[8192000 + i] = 0;
    // zero vhT swizzled pad slots: chunk 7, k 52..63 for every (bh, d)
    for (int i = t; i < 196608; i += stride) {
        int bh = i / 768;
        int r  = i - bh * 768;
        int d  = r / 12;
        int kk = 52 + (r - d * 12);
        vhT[((size_t)((bh * 8 + 7) * 64 + d)) * 64 + (kk ^ ((d & 7) << 3))] = 0;
    }
}

// ---------------------------------------------------------------------------
// Kernel 1: head projections, bf16 MFMA.
// grid (500, 2), block 512 = 8 waves in 2x4; block tile 64 rows x 256 cols.
// which=0: qh_bf [bh][500][64]
// which=1: vhT chunk-tiled+swizzled [bh][cc=8][d=64][k=64],
//          vhT[bh][cc][d][k ^ ((d&7)<<3)] = v_head[bh][d][cc*64+k]
// ---------------------------------------------------------------------------
__global__ __launch_bounds__(512) void proj_kernel(
    const float* __restrict__ q, const float* __restrict__ v,
    const u16* __restrict__ wqT, const u16* __restrict__ wvT,
    u16* __restrict__ qh_bf, u16* __restrict__ vhT)
{
    const int which = blockIdx.y;
    const float* __restrict__ x = which ? v : q;
    const u16*   __restrict__ wT = which ? wvT : wqT;

    __shared__ u16 Xs[64][72];    // [m][k], pad 144 B
    __shared__ u16 Ws[256][72];   // [n][k], pad 144 B

    const int tid  = threadIdx.x;
    const int wvid = tid >> 6, ln = tid & 63;
    const int n16  = ln & 15, quad = ln >> 4;
    const int wr   = wvid >> 2, wc = wvid & 3;   // 2 x 4
    const int row0 = blockIdx.x * 64;

    f32x4 acc[2][4];
    #pragma unroll
    for (int mt = 0; mt < 2; mt++)
        #pragma unroll
        for (int nt = 0; nt < 4; nt++) acc[mt][nt] = (f32x4){0.f, 0.f, 0.f, 0.f};

    for (int kc = 0; kc < 256; kc += 64) {
        // stage X (fp32 -> bf16): 64 x 64
        #pragma unroll
        for (int j = 0; j < 2; j++) {
            int idx = tid + 512 * j;
            int m = idx >> 4, k4 = idx & 15;
            float4 a = *(const float4*)&x[(size_t)(row0 + m) * 256 + kc + k4 * 4];
            __align__(8) u16 t4[4] = {f2bf(a.x), f2bf(a.y), f2bf(a.z), f2bf(a.w)};
            *(uint2*)&Xs[m][k4 * 4] = *(const uint2*)t4;
        }
        // stage W^T: 256 x 64 bf16
        #pragma unroll
        for (int j = 0; j < 4; j++) {
            int idx = tid + 512 * j;
            int n = idx >> 3, k8 = idx & 7;
            *(uint4*)&Ws[n][k8 * 8] = *(const uint4*)&wT[n * 256 + kc + k8 * 8];
        }
        __syncthreads();
        #pragma unroll
        for (int ks = 0; ks < 2; ks++) {
            short8 af[2], bfr[4];
            #pragma unroll
            for (int mt = 0; mt < 2; mt++)
                af[mt] = *(const short8*)&Xs[wr * 32 + mt * 16 + n16][ks * 32 + quad * 8];
            #pragma unroll
            for (int nt = 0; nt < 4; nt++)
                bfr[nt] = *(const short8*)&Ws[wc * 64 + nt * 16 + n16][ks * 32 + quad * 8];
            #pragma unroll
            for (int mt = 0; mt < 2; mt++)
                #pragma unroll
                for (int nt = 0; nt < 4; nt++)
                    acc[mt][nt] = __builtin_amdgcn_mfma_f32_16x16x32_bf16(
                        af[mt], bfr[nt], acc[mt][nt], 0, 0, 0);
        }
        __syncthreads();
    }

    // h = wc (64-col groups), d = nt*16 + n16
    if (which == 0) {
        #pragma unroll
        for (int mt = 0; mt < 2; mt++) {
            int m0 = row0 + wr * 32 + mt * 16 + quad * 4;   // mult of 4
            int b  = m0 / 500;
            int l0 = m0 - 500 * b;                           // group never straddles b
            #pragma unroll
            for (int nt = 0; nt < 4; nt++) {
                int d = nt * 16 + n16;
                u16* dst = qh_bf + ((size_t)((b * 4 + wc) * 500 + l0)) * 64 + d;
                #pragma unroll
                for (int i = 0; i < 4; i++)
                    dst[(size_t)i * 64] = f2bf(acc[mt][nt][i]);
            }
        }
    } else {
        #pragma unroll
        for (int mt = 0; mt < 2; mt++) {
            int m0 = row0 + wr * 32 + mt * 16 + quad * 4;
            int b  = m0 / 500;
            int l0 = m0 - 500 * b;                           // 4-aligned
            int cc = l0 >> 6, kk = l0 & 63;
            #pragma unroll
            for (int nt = 0; nt < 4; nt++) {
                int d = nt * 16 + n16;
                __align__(8) u16 t4[4];
                #pragma unroll
                for (int i = 0; i < 4; i++) t4[i] = f2bf(acc[mt][nt][i]);
                size_t base = ((size_t)(((b * 4 + wc) * 8 + cc) * 64 + d)) * 64;
                *(uint2*)&vhT[base + (kk ^ ((d & 7) << 3))] = *(const uint2*)t4;
            }
        }
    }
}

// ---------------------------------------------------------------------------
// Kernel 2: dense-synthesizer attention — w2-resident, V-streamed, 16 waves,
// ONE row-group per thread (fits the 64-VGPR budget the compiler insists on
// for 1024-thread blocks; R6-R8 all spilled 218MB with rg=2).
// grid (256 bh, 2 row-halves); block 1024 = 16 waves x 16 rows = 256 rows.
// LDS: w2 resident (64KB) + V dbuf (16KB) + scratch (36KB) + b2 = 120.8KB.
// Live state ~55 regs -> no spill at VGPR=64.
// ---------------------------------------------------------------------------
__global__ __launch_bounds__(1024) void attn_kernel(
    const u16* __restrict__ qh, const u16* __restrict__ vhT,
    const u16* __restrict__ w1T, const float* __restrict__ b1,
    const u16* __restrict__ w2sw, const float* __restrict__ b2p,
    u16* __restrict__ ctx)
{
    __shared__ __align__(16) u16 w2all[32768];     // [cc][row][k^swz], 64KB
    __shared__ __align__(16) u16 v_s[2][4096];     // [buf][d*64 + k^swz], 16KB
    __shared__ __align__(16) float b2s[512];
    __shared__ __align__(16) u16 scr[16][16][72];  // per-wave s / P scratch

    const int tid  = threadIdx.x;
    const int wv   = tid >> 6;       // 0..15
    const int ln   = tid & 63;
    const int n16  = ln & 15;
    const int quad = ln >> 4;
    const int bh   = blockIdx.x;
    const int r0   = blockIdx.y * 256 + wv * 16;   // this thread's 16-row group

    const u16* vg = vhT + (size_t)bh * 32768;

    // ---- (a) Phase-A input loads FIRST (oldest in vmcnt queue) ----
    short8 a0, a1;
    {
        const u16* qbase = qh + ((size_t)(bh * 500 + r0 + n16)) * 64;
        a0 = *(const short8*)(qbase + quad * 8);
        a1 = *(const short8*)(qbase + 32 + quad * 8);
    }
    short8 w1b0[4], w1b1[4];
    float  b1v[4];
    #pragma unroll
    for (int nt = 0; nt < 4; nt++) {
        const u16* wb = w1T + (nt * 16 + n16) * 64;
        w1b0[nt] = *(const short8*)(wb + quad * 8);
        w1b1[nt] = *(const short8*)(wb + 32 + quad * 8);
        b1v[nt]  = b1[nt * 16 + n16];
    }
    __builtin_amdgcn_sched_barrier(0);

    // ---- (b) one-shot staging: all of w2 (4 DMA/wave), v[0], b2 ----
    {
        int base = wv * 2048;           // 2048 u16 per wave (4 KB)
        #pragma unroll
        for (int j = 0; j < 4; j++)
            gload_lds16(w2sw + base + j * 512 + ln * 8, &w2all[base + j * 512]);
        if (wv < 8)
            gload_lds16(vg + wv * 512 + ln * 8, &v_s[0][wv * 512]);
        if (wv >= 14)
            gload_lds16((const u16*)b2p + (wv - 14) * 512 + ln * 8,
                        (u16*)&b2s[(wv - 14) * 256]);
    }
    __builtin_amdgcn_sched_barrier(0);

    // ---- (c) Phase A: s = relu(qh @ w1 + b1) ----
    short8 sa0, sa1;
    {
        #pragma unroll
        for (int nt = 0; nt < 4; nt++) {
            float bias = b1v[nt];
            f32x4 c = {bias, bias, bias, bias};
            c = __builtin_amdgcn_mfma_f32_16x16x32_bf16(a0, w1b0[nt], c, 0, 0, 0);
            c = __builtin_amdgcn_mfma_f32_16x16x32_bf16(a1, w1b1[nt], c, 0, 0, 0);
            int col = nt * 16 + n16;
            #pragma unroll
            for (int i = 0; i < 4; i++)
                scr[wv][quad * 4 + i][col] = f2bf(fmaxf(c[i], 0.f));
        }
        sa0 = *(const short8*)&scr[wv][n16][quad * 8];
        sa1 = *(const short8*)&scr[wv][n16][32 + quad * 8];
    }

    f32x4 oacc[4];
    #pragma unroll
    for (int nt = 0; nt < 4; nt++) oacc[nt] = (f32x4){0.f, 0.f, 0.f, 0.f};
    float sm[4] = {0.f, 0.f, 0.f, 0.f};

    __syncthreads();   // staging complete (w2all, v[0], b2s ready)

    // ---- (d) main: 8 chunks; barrier only for V dbuf ----
    #pragma unroll 2
    for (int cc = 0; cc < 8; cc++) {
        if (cc < 7 && wv < 8)   // stage next V chunk into the other buffer
            gload_lds16(vg + (cc + 1) * 4096 + wv * 512 + ln * 8,
                        &v_s[(cc + 1) & 1][wv * 512]);
        const u16* vbuf = &v_s[cc & 1][0];

        // logits: 4 col-tiles of 16 (w2 resident in LDS)
        f32x4 c8[4];
        #pragma unroll
        for (int t = 0; t < 4; t++) {
            int r  = t * 16 + n16;
            int sw = (r & 7) << 3;
            const u16* wb = &w2all[cc * 4096 + r * 64];
            short8 b0  = *(const short8*)&wb[(quad * 8) ^ sw];
            short8 b1f = *(const short8*)&wb[(32 + quad * 8) ^ sw];
            float bias = b2s[cc * 64 + r];
            f32x4 c = {bias, bias, bias, bias};
            c = __builtin_amdgcn_mfma_f32_16x16x32_bf16(sa0, b0, c, 0, 0, 0);
            c = __builtin_amdgcn_mfma_f32_16x16x32_bf16(sa1, b1f, c, 0, 0, 0);
            c8[t] = c;
        }
        // exp (no max-pass) + running sum; P -> bf16 (half-up) -> scratch
        #pragma unroll
        for (int t = 0; t < 4; t++) {
            int col = t * 16 + n16;
            #pragma unroll
            for (int i = 0; i < 4; i++) {
                float e = __expf(c8[t][i]);
                sm[i] += e;
                scr[wv][quad * 4 + i][col] = f2bf_up(e);
            }
        }
        // PV on this chunk
        #pragma unroll
        for (int ks = 0; ks < 2; ks++) {
            short8 pa = *(const short8*)&scr[wv][n16][ks * 32 + quad * 8];
            #pragma unroll
            for (int nt = 0; nt < 4; nt++) {
                int d   = nt * 16 + n16;
                int swd = (d & 7) << 3;
                short8 vb2 = *(const short8*)&vbuf[d * 64 +
                                                   ((ks * 32 + quad * 8) ^ swd)];
                oacc[nt] = __builtin_amdgcn_mfma_f32_16x16x32_bf16(
                    pa, vb2, oacc[nt], 0, 0, 0);
            }
        }
        __syncthreads();   // next V staged; all waves done with current buffer
    }

    // ---- epilogue: row-sum reduce, scaled bf16 store ----
    const int b = bh >> 2, h = bh & 3;
    #pragma unroll
    for (int off = 1; off < 16; off <<= 1) {
        #pragma unroll
        for (int i = 0; i < 4; i++) sm[i] += __shfl_xor(sm[i], off);
    }
    #pragma unroll
    for (int i = 0; i < 4; i++) {
        int lrow = r0 + quad * 4 + i;
        if (lrow < 500) {
            float s = 1.f / sm[i];
            u16* dst = &ctx[((size_t)(b * 500 + lrow)) * 256 + h * 64];
            #pragma unroll
            for (int nt = 0; nt < 4; nt++)
                dst[nt * 16 + n16] = f2bf(oacc[nt][i] * s);
        }
    }
}

// ---------------------------------------------------------------------------
// Kernel 3: out = LayerNorm(ctx @ fc_w + q), bf16 MFMA + fused LN epilogue.
// grid (500), block 512 = 8 waves in 2x4; block tile 64 rows x 256 cols.
// ---------------------------------------------------------------------------
__global__ __launch_bounds__(512) void final_kernel(
    const u16* __restrict__ ctx, const u16* __restrict__ fcwT,
    const float* __restrict__ qres, const float* __restrict__ g,
    const float* __restrict__ bta, float* __restrict__ out)
{
    __shared__ u16 Xs[64][72];
    __shared__ u16 Ws[256][72];
    __shared__ float red[4][2][64];   // [wc][s1|s2][row]
    __shared__ float murs[2][64];     // [mu|rs][row]

    const int tid  = threadIdx.x;
    const int wvid = tid >> 6, ln = tid & 63;
    const int n16  = ln & 15, quad = ln >> 4;
    const int wr   = wvid >> 2, wc = wvid & 3;   // 2 x 4
    const int row0 = blockIdx.x * 64;

    f32x4 acc[2][4];
    #pragma unroll
    for (int mt = 0; mt < 2; mt++)
        #pragma unroll
        for (int nt = 0; nt < 4; nt++) acc[mt][nt] = (f32x4){0.f, 0.f, 0.f, 0.f};

    for (int kc = 0; kc < 256; kc += 64) {
        // stage X: 64 x 64 bf16
        {
            int idx = tid;
            int m = idx >> 3, k8 = idx & 7;
            *(uint4*)&Xs[m][k8 * 8] =
                *(const uint4*)&ctx[(size_t)(row0 + m) * 256 + kc + k8 * 8];
        }
        // stage W^T: 256 x 64 bf16
        #pragma unroll
        for (int j = 0; j < 4; j++) {
            int idx = tid + 512 * j;
            int n = idx >> 3, k8 = idx & 7;
            *(uint4*)&Ws[n][k8 * 8] = *(const uint4*)&fcwT[n * 256 + kc + k8 * 8];
        }
        __syncthreads();
        #pragma unroll
        for (int ks = 0; ks < 2; ks++) {
            short8 af[2], bfr[4];
            #pragma unroll
            for (int mt = 0; mt < 2; mt++)
                af[mt] = *(const short8*)&Xs[wr * 32 + mt * 16 + n16][ks * 32 + quad * 8];
            #pragma unroll
            for (int nt = 0; nt < 4; nt++)
                bfr[nt] = *(const short8*)&Ws[wc * 64 + nt * 16 + n16][ks * 32 + quad * 8];
            #pragma unroll
            for (int mt = 0; mt < 2; mt++)
                #pragma unroll
                for (int nt = 0; nt < 4; nt++)
                    acc[mt][nt] = __builtin_amdgcn_mfma_f32_16x16x32_bf16(
                        af[mt], bfr[nt], acc[mt][nt], 0, 0, 0);
        }
        __syncthreads();
    }

    // residual add
    #pragma unroll
    for (int mt = 0; mt < 2; mt++) {
        int m0 = row0 + wr * 32 + mt * 16 + quad * 4;
        #pragma unroll
        for (int i = 0; i < 4; i++) {
            const float* rp = &qres[(size_t)(m0 + i) * 256 + wc * 64 + n16];
            #pragma unroll
            for (int nt = 0; nt < 4; nt++)
                acc[mt][nt][i] += rp[nt * 16];
        }
    }
    // per-row partial sums -> LDS
    #pragma unroll
    for (int mt = 0; mt < 2; mt++) {
        #pragma unroll
        for (int i = 0; i < 4; i++) {
            float s1 = 0.f, s2 = 0.f;
            #pragma unroll
            for (int nt = 0; nt < 4; nt++) {
                float vv = acc[mt][nt][i];
                s1 += vv; s2 += vv * vv;
            }
            #pragma unroll
            for (int off = 1; off < 16; off <<= 1) {
                s1 += __shfl_xor(s1, off);
                s2 += __shfl_xor(s2, off);
            }
            if (n16 == 0) {
                int r = wr * 32 + mt * 16 + quad * 4 + i;
                red[wc][0][r] = s1;
                red[wc][1][r] = s2;
            }
        }
    }
    __syncthreads();
    if (tid < 64) {
        float S1 = red[0][0][tid] + red[1][0][tid] + red[2][0][tid] + red[3][0][tid];
        float S2 = red[0][1][tid] + red[1][1][tid] + red[2][1][tid] + red[3][1][tid];
        float mu  = S1 * 0.00390625f;
        float var = S2 * 0.00390625f - mu * mu;
        murs[0][tid] = mu;
        murs[1][tid] = rsqrtf(var + 1e-6f);
    }
    __syncthreads();

    float gv[4], bv[4];
    #pragma unroll
    for (int nt = 0; nt < 4; nt++) {
        int col = wc * 64 + nt * 16 + n16;
        gv[nt] = g[col];
        bv[nt] = bta[col];
    }
    #pragma unroll
    for (int mt = 0; mt < 2; mt++) {
        int rb = wr * 32 + mt * 16 + quad * 4;
        #pragma unroll
        for (int i = 0; i < 4; i++) {
            float mu = murs[0][rb + i];
            float rs = murs[1][rb + i];
            float* op = &out[(size_t)(row0 + rb + i) * 256 + wc * 64 + n16];
            #pragma unroll
            for (int nt = 0; nt < 4; nt++)
                op[nt * 16] = (acc[mt][nt][i] - mu) * rs * gv[nt] + bv[nt];
        }
    }
}

// ---------------------------------------------------------------------------
extern "C" void kernel_launch(void* const* d_in, const int* in_sizes, int n_in,
                              void* d_out, int out_size, void* d_ws, size_t ws_size,
                              hipStream_t stream)
{
    const float* q   = (const float*)d_in[0];
    const float* v   = (const float*)d_in[2];
    const float* wqs = (const float*)d_in[3];
    const float* wvs = (const float*)d_in[4];
    const float* w1  = (const float*)d_in[5];
    const float* b1  = (const float*)d_in[6];
    const float* w2  = (const float*)d_in[7];
    const float* b2  = (const float*)d_in[8];
    const float* fcw = (const float*)d_in[9];
    const float* lng = (const float*)d_in[10];
    const float* lnb = (const float*)d_in[11];
    float* out = (float*)d_out;

    u16* qh_bf = (u16*)d_ws;            // 8,200,192 (rows >=500*256 are pad)
    u16* vhT   = qh_bf + 8200192;       // 8,388,608 (chunk-tiled + swizzled)
    u16* w1T   = vhT + 8388608;         // 4,096
    u16* w2sw  = w1T + 4096;            // 32,768 (chunk-tiled + swizzled)
    u16* wqT   = w2sw + 32768;          // 65,536
    u16* wvT   = wqT + 65536;           // 65,536
    u16* fcwT  = wvT + 65536;           // 65,536
    u16* ctx   = fcwT + 65536;          // 8,192,000
    float* b2p = (float*)(qh_bf + 8195072);  // 512 floats inside qh_bf tail pad

    prep_kernel <<<dim3(64),     256, 0, stream>>>(wqs, wvs, fcw, w1, w2, b2,
                                                   wqT, wvT, fcwT, w1T, w2sw,
                                                   qh_bf, vhT, b2p);
    proj_kernel <<<dim3(500, 2), 512, 0, stream>>>(q, v, wqT, wvT, qh_bf, vhT);
    attn_kernel <<<dim3(256, 2),1024, 0, stream>>>(qh_bf, vhT, w1T, b1, w2sw, b2p, ctx);
    final_kernel<<<dim3(500),    512, 0, stream>>>(ctx, fcwT, q, lng, lnb, out);
}

// Round 10
// 86.321 us; speedup vs baseline: 1.4167x; 1.0751x over previous
//
#include <hip/hip_runtime.h>
#include <math.h>

#define B_   64
#define L_   500
#define F_   256
#define H_   4
#define DK   64
#define LOG2E 1.44269504088896340736f

typedef unsigned short u16;
typedef unsigned int   u32;
typedef __attribute__((ext_vector_type(8))) short short8;
typedef __attribute__((ext_vector_type(4))) float f32x4;

static __device__ __forceinline__ u16 f2bf(float f) {
    u32 u = __float_as_uint(f);
    u32 r = (u + 0x7FFFu + ((u >> 16) & 1u)) >> 16;
    return (u16)r;
}
// pack two floats to 2x bf16 (round-half-up) in one u32: {hi=y, lo=x}
static __device__ __forceinline__ u32 pk_bf16_up(float x, float y) {
    u32 xb = __float_as_uint(x) + 0x8000u;
    u32 yb = __float_as_uint(y) + 0x8000u;
    return (xb >> 16) | (yb & 0xFFFF0000u);
}
static __device__ __forceinline__ float exp2_fast(float x) {
#if __has_builtin(__builtin_amdgcn_exp2f)
    return __builtin_amdgcn_exp2f(x);
#else
    return exp2f(x);
#endif
}

typedef __attribute__((address_space(3))) u32 lds32;
typedef const __attribute__((address_space(1))) u32 gbl32;
// async global->LDS DMA, 16 B/lane, LDS dest = uniform base + lane*16
static __device__ __forceinline__ void gload_lds16(const u16* g, u16* l) {
    __builtin_amdgcn_global_load_lds((gbl32*)g, (lds32*)l, 16, 0, 0);
}

// ---------------------------------------------------------------------------
// Prep: bf16 transposed weights + padded b2 + pad-zeroing of ws regions.
//  wqT/wvT/fcwT [256][256] ([n][k]); w1T[64][64]
//  w2sw: chunk-tiled + XOR-swizzled + PRE-SCALED by log2(e):
//        w2sw[cc][row][k] = log2e * w2[k ^ ((row&7)<<3)][cc*64+row]
//  b2p[512] float = log2e * b2 (tail -1e30 -> exp2() == 0)
// ---------------------------------------------------------------------------
__global__ __launch_bounds__(256) void prep_kernel(
    const float* __restrict__ wq, const float* __restrict__ wv,
    const float* __restrict__ fcw, const float* __restrict__ w1,
    const float* __restrict__ w2, const float* __restrict__ b2,
    u16* __restrict__ wqT, u16* __restrict__ wvT, u16* __restrict__ fcwT,
    u16* __restrict__ w1T, u16* __restrict__ w2sw,
    u16* __restrict__ qh_bf, u16* __restrict__ vhT, float* __restrict__ b2p)
{
    int t = blockIdx.x * 256 + threadIdx.x;
    int stride = gridDim.x * 256;                 // 16384
    for (int i = t; i < 256 * 256; i += stride) {
        int n = i >> 8, k = i & 255;
        wqT[i]  = f2bf(wq[k * 256 + n]);
        wvT[i]  = f2bf(wv[k * 256 + n]);
        fcwT[i] = f2bf(fcw[k * 256 + n]);
    }
    for (int i = t; i < 64 * 64; i += stride) {
        int n = i >> 6, k = i & 63;
        w1T[i] = f2bf(w1[k * 64 + n]);
    }
    // w2 chunk-tiled + swizzled + log2e-scaled
    for (int i = t; i < 512 * 64; i += stride) {
        int cc  = i >> 12;
        int row = (i >> 6) & 63;
        int kc  = i & 63;
        int n   = cc * 64 + row;
        int kl  = kc ^ ((row & 7) << 3);
        w2sw[i] = f2bf((n < 500 ? w2[kl * 500 + n] : 0.f) * LOG2E);
    }
    // padded, scaled bias (tail -> exp2() == 0)
    for (int i = t; i < 512; i += stride)
        b2p[i] = (i < 500) ? b2[i] * LOG2E : -1e30f;
    // zero qh_bf pad rows read by attn (rows >= 128000); b2p lives at 8195072+
    for (int i = t; i < 3072; i += stride)
        qh_bf[8192000 + i] = 0;
    // zero vhT swizzled pad slots: chunk 7, k 52..63 for every (bh, d)
    for (int i = t; i < 196608; i += stride) {
        int bh = i / 768;
        int r  = i - bh * 768;
        int d  = r / 12;
        int kk = 52 + (r - d * 12);
        vhT[((size_t)((bh * 8 + 7) * 64 + d)) * 64 + (kk ^ ((d & 7) << 3))] = 0;
    }
}

// ---------------------------------------------------------------------------
// Kernel 1: head projections, bf16 MFMA.
// grid (500, 2), block 512 = 8 waves in 2x4; block tile 64 rows x 256 cols.
// which=0: qh_bf [bh][500][64]
// which=1: vhT chunk-tiled+swizzled [bh][cc=8][d=64][k=64],
//          vhT[bh][cc][d][k ^ ((d&7)<<3)] = v_head[bh][d][cc*64+k]
// ---------------------------------------------------------------------------
__global__ __launch_bounds__(512) void proj_kernel(
    const float* __restrict__ q, const float* __restrict__ v,
    const u16* __restrict__ wqT, const u16* __restrict__ wvT,
    u16* __restrict__ qh_bf, u16* __restrict__ vhT)
{
    const int which = blockIdx.y;
    const float* __restrict__ x = which ? v : q;
    const u16*   __restrict__ wT = which ? wvT : wqT;

    __shared__ u16 Xs[64][72];    // [m][k], pad 144 B
    __shared__ u16 Ws[256][72];   // [n][k], pad 144 B

    const int tid  = threadIdx.x;
    const int wvid = tid >> 6, ln = tid & 63;
    const int n16  = ln & 15, quad = ln >> 4;
    const int wr   = wvid >> 2, wc = wvid & 3;   // 2 x 4
    const int row0 = blockIdx.x * 64;

    f32x4 acc[2][4];
    #pragma unroll
    for (int mt = 0; mt < 2; mt++)
        #pragma unroll
        for (int nt = 0; nt < 4; nt++) acc[mt][nt] = (f32x4){0.f, 0.f, 0.f, 0.f};

    for (int kc = 0; kc < 256; kc += 64) {
        // stage X (fp32 -> bf16): 64 x 64
        #pragma unroll
        for (int j = 0; j < 2; j++) {
            int idx = tid + 512 * j;
            int m = idx >> 4, k4 = idx & 15;
            float4 a = *(const float4*)&x[(size_t)(row0 + m) * 256 + kc + k4 * 4];
            __align__(8) u16 t4[4] = {f2bf(a.x), f2bf(a.y), f2bf(a.z), f2bf(a.w)};
            *(uint2*)&Xs[m][k4 * 4] = *(const uint2*)t4;
        }
        // stage W^T: 256 x 64 bf16
        #pragma unroll
        for (int j = 0; j < 4; j++) {
            int idx = tid + 512 * j;
            int n = idx >> 3, k8 = idx & 7;
            *(uint4*)&Ws[n][k8 * 8] = *(const uint4*)&wT[n * 256 + kc + k8 * 8];
        }
        __syncthreads();
        #pragma unroll
        for (int ks = 0; ks < 2; ks++) {
            short8 af[2], bfr[4];
            #pragma unroll
            for (int mt = 0; mt < 2; mt++)
                af[mt] = *(const short8*)&Xs[wr * 32 + mt * 16 + n16][ks * 32 + quad * 8];
            #pragma unroll
            for (int nt = 0; nt < 4; nt++)
                bfr[nt] = *(const short8*)&Ws[wc * 64 + nt * 16 + n16][ks * 32 + quad * 8];
            #pragma unroll
            for (int mt = 0; mt < 2; mt++)
                #pragma unroll
                for (int nt = 0; nt < 4; nt++)
                    acc[mt][nt] = __builtin_amdgcn_mfma_f32_16x16x32_bf16(
                        af[mt], bfr[nt], acc[mt][nt], 0, 0, 0);
        }
        __syncthreads();
    }

    // h = wc (64-col groups), d = nt*16 + n16
    if (which == 0) {
        #pragma unroll
        for (int mt = 0; mt < 2; mt++) {
            int m0 = row0 + wr * 32 + mt * 16 + quad * 4;   // mult of 4
            int b  = m0 / 500;
            int l0 = m0 - 500 * b;                           // group never straddles b
            #pragma unroll
            for (int nt = 0; nt < 4; nt++) {
                int d = nt * 16 + n16;
                u16* dst = qh_bf + ((size_t)((b * 4 + wc) * 500 + l0)) * 64 + d;
                #pragma unroll
                for (int i = 0; i < 4; i++)
                    dst[(size_t)i * 64] = f2bf(acc[mt][nt][i]);
            }
        }
    } else {
        #pragma unroll
        for (int mt = 0; mt < 2; mt++) {
            int m0 = row0 + wr * 32 + mt * 16 + quad * 4;
            int b  = m0 / 500;
            int l0 = m0 - 500 * b;                           // 4-aligned
            int cc = l0 >> 6, kk = l0 & 63;
            #pragma unroll
            for (int nt = 0; nt < 4; nt++) {
                int d = nt * 16 + n16;
                __align__(8) u16 t4[4];
                #pragma unroll
                for (int i = 0; i < 4; i++) t4[i] = f2bf(acc[mt][nt][i]);
                size_t base = ((size_t)(((b * 4 + wc) * 8 + cc) * 64 + d)) * 64;
                *(uint2*)&vhT[base + (kk ^ ((d & 7) << 3))] = *(const uint2*)t4;
            }
        }
    }
}

// ---------------------------------------------------------------------------
// Kernel 2: dense-synthesizer attention — LDS-bandwidth-optimized.
// grid (256) = 1 block/bh/CU, ONE grid round; block 512 = 8 waves.
// Each wave: 32 rows (2 rgs of 16), sequential rh halves (0..255, 256..499).
// Key levers vs R9 (which was LDS-read-throughput-bound at ~5400 cy/chunk):
//  - B-fragments (w2, V) read ONCE per wave, feed BOTH rgs (2x amortization)
//  - swapped-operand logits: D = mfma(A=w2^T-frag, B=s-frag) gives lane 4
//    adjacent COLS of one row -> P stored as packed b64 (8 writes vs 32 u16),
//    bias as one float4 read, sm one scalar per rg
//  - exp2 with log2e folded into w2/b2 at prep (1 VALU per exp)
//  - w2 staged once per bh (rh loop inside block; V dbuf parity carries over)
// LDS ops/chunk/wave: 24 b128 reads + 8 b64 writes per 32 rows = 0.50x R9.
// ---------------------------------------------------------------------------
__global__ __launch_bounds__(512, 1) void attn_kernel(
    const u16* __restrict__ qh, const u16* __restrict__ vhT,
    const u16* __restrict__ w1T, const float* __restrict__ b1,
    const u16* __restrict__ w2sw, const float* __restrict__ b2p,
    u16* __restrict__ ctx)
{
    __shared__ __align__(16) u16 w2all[32768];       // [cc][row][k^swz], 64KB
    __shared__ __align__(16) u16 v_s[2][4096];       // [buf][d*64 + k^swz], 16KB
    __shared__ __align__(16) float b2s[512];         // scaled bias, 2KB
    __shared__ __align__(16) u16 scr[8][2][16][72];  // per-wave/rg s,P scratch

    const int tid  = threadIdx.x;
    const int wv   = tid >> 6;       // 0..7
    const int ln   = tid & 63;
    const int n16  = ln & 15;
    const int quad = ln >> 4;
    const int bh   = blockIdx.x;

    const u16* vg = vhT + (size_t)bh * 32768;

    // ---- one-shot staging: all of w2 (8 DMA/wave), v[0], b2 ----
    {
        int base = wv * 4096;
        #pragma unroll
        for (int j = 0; j < 8; j++)
            gload_lds16(w2sw + base + j * 512 + ln * 8, &w2all[base + j * 512]);
        gload_lds16(vg + wv * 512 + ln * 8, &v_s[0][wv * 512]);
        if (wv < 2)
            gload_lds16((const u16*)b2p + wv * 512 + ln * 8, (u16*)&b2s[wv * 256]);
    }

    const int b = bh >> 2, h = bh & 3;

    for (int rh = 0; rh < 2; rh++) {
        const int r0 = rh * 256 + wv * 32;

        // ---- Phase A (swapped): s = relu(qh @ w1 + b1) -> packed scr ----
        {
            short8 a0[2], a1[2];
            #pragma unroll
            for (int rg = 0; rg < 2; rg++) {
                const u16* qbase =
                    qh + ((size_t)(bh * 500 + r0 + rg * 16 + n16)) * 64;
                a0[rg] = *(const short8*)(qbase + quad * 8);
                a1[rg] = *(const short8*)(qbase + 32 + quad * 8);
            }
            #pragma unroll
            for (int nt = 0; nt < 4; nt++) {
                const u16* wb = w1T + (nt * 16 + n16) * 64;
                short8 wA0 = *(const short8*)(wb + quad * 8);
                short8 wA1 = *(const short8*)(wb + 32 + quad * 8);
                float4 bv = *(const float4*)&b1[nt * 16 + quad * 4];
                #pragma unroll
                for (int rg = 0; rg < 2; rg++) {
                    f32x4 c = {bv.x, bv.y, bv.z, bv.w};
                    c = __builtin_amdgcn_mfma_f32_16x16x32_bf16(wA0, a0[rg], c, 0, 0, 0);
                    c = __builtin_amdgcn_mfma_f32_16x16x32_bf16(wA1, a1[rg], c, 0, 0, 0);
                    u32 p01 = pk_bf16_up(fmaxf(c[0], 0.f), fmaxf(c[1], 0.f));
                    u32 p23 = pk_bf16_up(fmaxf(c[2], 0.f), fmaxf(c[3], 0.f));
                    *(uint2*)&scr[wv][rg][n16][nt * 16 + quad * 4] =
                        make_uint2(p01, p23);
                }
            }
        }
        short8 sa0[2], sa1[2];
        #pragma unroll
        for (int rg = 0; rg < 2; rg++) {
            sa0[rg] = *(const short8*)&scr[wv][rg][n16][quad * 8];
            sa1[rg] = *(const short8*)&scr[wv][rg][n16][32 + quad * 8];
        }

        f32x4 oacc[2][4];
        #pragma unroll
        for (int rg = 0; rg < 2; rg++)
            #pragma unroll
            for (int nt = 0; nt < 4; nt++)
                oacc[rg][nt] = (f32x4){0.f, 0.f, 0.f, 0.f};
        float sm[2] = {0.f, 0.f};

        if (rh == 0) __syncthreads();   // prologue staging complete

        // ---- main: 8 chunks; B-frags shared across rgs ----
        #pragma unroll 2
        for (int cc = 0; cc < 8; cc++) {
            if (!(rh == 1 && cc == 7))   // V dbuf parity carries across rh
                gload_lds16(vg + ((cc + 1) & 7) * 4096 + wv * 512 + ln * 8,
                            &v_s[(cc + 1) & 1][wv * 512]);
            const u16* vbuf = &v_s[cc & 1][0];

            // logits (swapped) + exp2 + pack -> scr, per t-tile
            #pragma unroll
            for (int t = 0; t < 4; t++) {
                int r  = t * 16 + n16;
                int sw = (r & 7) << 3;
                const u16* wb = &w2all[cc * 4096 + r * 64];
                short8 wA0 = *(const short8*)&wb[(quad * 8) ^ sw];
                short8 wA1 = *(const short8*)&wb[(32 + quad * 8) ^ sw];
                float4 bv = *(const float4*)&b2s[cc * 64 + t * 16 + quad * 4];
                #pragma unroll
                for (int rg = 0; rg < 2; rg++) {
                    f32x4 c = {bv.x, bv.y, bv.z, bv.w};
                    c = __builtin_amdgcn_mfma_f32_16x16x32_bf16(wA0, sa0[rg], c, 0, 0, 0);
                    c = __builtin_amdgcn_mfma_f32_16x16x32_bf16(wA1, sa1[rg], c, 0, 0, 0);
                    float e0 = exp2_fast(c[0]);
                    float e1 = exp2_fast(c[1]);
                    float e2 = exp2_fast(c[2]);
                    float e3 = exp2_fast(c[3]);
                    sm[rg] += (e0 + e1) + (e2 + e3);
                    *(uint2*)&scr[wv][rg][n16][t * 16 + quad * 4] =
                        make_uint2(pk_bf16_up(e0, e1), pk_bf16_up(e2, e3));
                }
            }
            // PV: V-frag read once, feeds both rgs
            #pragma unroll
            for (int ks = 0; ks < 2; ks++) {
                short8 pa0 = *(const short8*)&scr[wv][0][n16][ks * 32 + quad * 8];
                short8 pa1 = *(const short8*)&scr[wv][1][n16][ks * 32 + quad * 8];
                #pragma unroll
                for (int nt = 0; nt < 4; nt++) {
                    int d   = nt * 16 + n16;
                    int swd = (d & 7) << 3;
                    short8 vb = *(const short8*)&vbuf[d * 64 +
                                                      ((ks * 32 + quad * 8) ^ swd)];
                    oacc[0][nt] = __builtin_amdgcn_mfma_f32_16x16x32_bf16(
                        pa0, vb, oacc[0][nt], 0, 0, 0);
                    oacc[1][nt] = __builtin_amdgcn_mfma_f32_16x16x32_bf16(
                        pa1, vb, oacc[1][nt], 0, 0, 0);
                }
            }
            __syncthreads();   // next V staged; buffer safe to flip
        }

        // ---- epilogue: row-sum reduce + scaled bf16 store ----
        #pragma unroll
        for (int rg = 0; rg < 2; rg++) {
            float smt = sm[rg];
            smt += __shfl_xor(smt, 16);
            smt += __shfl_xor(smt, 32);   // lane now holds total for row n16
            #pragma unroll
            for (int i = 0; i < 4; i++) {
                int lrow = r0 + rg * 16 + quad * 4 + i;
                float si = __shfl(smt, quad * 4 + i);   // row (quad*4+i)'s sum
                if (lrow < 500) {
                    float s = 1.f / si;
                    u16* dst = &ctx[((size_t)(b * 500 + lrow)) * 256 + h * 64];
                    #pragma unroll
                    for (int nt = 0; nt < 4; nt++)
                        dst[nt * 16 + n16] = f2bf(oacc[rg][nt][i] * s);
                }
            }
        }
    }
}

// ---------------------------------------------------------------------------
// Kernel 3: out = LayerNorm(ctx @ fc_w + q), bf16 MFMA + fused LN epilogue.
// grid (500), block 512 = 8 waves in 2x4; block tile 64 rows x 256 cols.
// ---------------------------------------------------------------------------
__global__ __launch_bounds__(512) void final_kernel(
    const u16* __restrict__ ctx, const u16* __restrict__ fcwT,
    const float* __restrict__ qres, const float* __restrict__ g,
    const float* __restrict__ bta, float* __restrict__ out)
{
    __shared__ u16 Xs[64][72];
    __shared__ u16 Ws[256][72];
    __shared__ float red[4][2][64];   // [wc][s1|s2][row]
    __shared__ float murs[2][64];     // [mu|rs][row]

    const int tid  = threadIdx.x;
    const int wvid = tid >> 6, ln = tid & 63;
    const int n16  = ln & 15, quad = ln >> 4;
    const int wr   = wvid >> 2, wc = wvid & 3;   // 2 x 4
    const int row0 = blockIdx.x * 64;

    f32x4 acc[2][4];
    #pragma unroll
    for (int mt = 0; mt < 2; mt++)
        #pragma unroll
        for (int nt = 0; nt < 4; nt++) acc[mt][nt] = (f32x4){0.f, 0.f, 0.f, 0.f};

    for (int kc = 0; kc < 256; kc += 64) {
        // stage X: 64 x 64 bf16
        {
            int idx = tid;
            int m = idx >> 3, k8 = idx & 7;
            *(uint4*)&Xs[m][k8 * 8] =
                *(const uint4*)&ctx[(size_t)(row0 + m) * 256 + kc + k8 * 8];
        }
        // stage W^T: 256 x 64 bf16
        #pragma unroll
        for (int j = 0; j < 4; j++) {
            int idx = tid + 512 * j;
            int n = idx >> 3, k8 = idx & 7;
            *(uint4*)&Ws[n][k8 * 8] = *(const uint4*)&fcwT[n * 256 + kc + k8 * 8];
        }
        __syncthreads();
        #pragma unroll
        for (int ks = 0; ks < 2; ks++) {
            short8 af[2], bfr[4];
            #pragma unroll
            for (int mt = 0; mt < 2; mt++)
                af[mt] = *(const short8*)&Xs[wr * 32 + mt * 16 + n16][ks * 32 + quad * 8];
            #pragma unroll
            for (int nt = 0; nt < 4; nt++)
                bfr[nt] = *(const short8*)&Ws[wc * 64 + nt * 16 + n16][ks * 32 + quad * 8];
            #pragma unroll
            for (int mt = 0; mt < 2; mt++)
                #pragma unroll
                for (int nt = 0; nt < 4; nt++)
                    acc[mt][nt] = __builtin_amdgcn_mfma_f32_16x16x32_bf16(
                        af[mt], bfr[nt], acc[mt][nt], 0, 0, 0);
        }
        __syncthreads();
    }

    // residual add
    #pragma unroll
    for (int mt = 0; mt < 2; mt++) {
        int m0 = row0 + wr * 32 + mt * 16 + quad * 4;
        #pragma unroll
        for (int i = 0; i < 4; i++) {
            const float* rp = &qres[(size_t)(m0 + i) * 256 + wc * 64 + n16];
            #pragma unroll
            for (int nt = 0; nt < 4; nt++)
                acc[mt][nt][i] += rp[nt * 16];
        }
    }
    // per-row partial sums -> LDS
    #pragma unroll
    for (int mt = 0; mt < 2; mt++) {
        #pragma unroll
        for (int i = 0; i < 4; i++) {
            float s1 = 0.f, s2 = 0.f;
            #pragma unroll
            for (int nt = 0; nt < 4; nt++) {
                float vv = acc[mt][nt][i];
                s1 += vv; s2 += vv * vv;
            }
            #pragma unroll
            for (int off = 1; off < 16; off <<= 1) {
                s1 += __shfl_xor(s1, off);
                s2 += __shfl_xor(s2, off);
            }
            if (n16 == 0) {
                int r = wr * 32 + mt * 16 + quad * 4 + i;
                red[wc][0][r] = s1;
                red[wc][1][r] = s2;
            }
        }
    }
    __syncthreads();
    if (tid < 64) {
        float S1 = red[0][0][tid] + red[1][0][tid] + red[2][0][tid] + red[3][0][tid];
        float S2 = red[0][1][tid] + red[1][1][tid] + red[2][1][tid] + red[3][1][tid];
        float mu  = S1 * 0.00390625f;
        float var = S2 * 0.00390625f - mu * mu;
        murs[0][tid] = mu;
        murs[1][tid] = rsqrtf(var + 1e-6f);
    }
    __syncthreads();

    float gv[4], bv[4];
    #pragma unroll
    for (int nt = 0; nt < 4; nt++) {
        int col = wc * 64 + nt * 16 + n16;
        gv[nt] = g[col];
        bv[nt] = bta[col];
    }
    #pragma unroll
    for (int mt = 0; mt < 2; mt++) {
        int rb = wr * 32 + mt * 16 + quad * 4;
        #pragma unroll
        for (int i = 0; i < 4; i++) {
            float mu = murs[0][rb + i];
            float rs = murs[1][rb + i];
            float* op = &out[(size_t)(row0 + rb + i) * 256 + wc * 64 + n16];
            #pragma unroll
            for (int nt = 0; nt < 4; nt++)
                op[nt * 16] = (acc[mt][nt][i] - mu) * rs * gv[nt] + bv[nt];
        }
    }
}

// ---------------------------------------------------------------------------
extern "C" void kernel_launch(void* const* d_in, const int* in_sizes, int n_in,
                              void* d_out, int out_size, void* d_ws, size_t ws_size,
                              hipStream_t stream)
{
    const float* q   = (const float*)d_in[0];
    const float* v   = (const float*)d_in[2];
    const float* wqs = (const float*)d_in[3];
    const float* wvs = (const float*)d_in[4];
    const float* w1  = (const float*)d_in[5];
    const float* b1  = (const float*)d_in[6];
    const float* w2  = (const float*)d_in[7];
    const float* b2  = (const float*)d_in[8];
    const float* fcw = (const float*)d_in[9];
    const float* lng = (const float*)d_in[10];
    const float* lnb = (const float*)d_in[11];
    float* out = (float*)d_out;

    u16* qh_bf = (u16*)d_ws;            // 8,200,192 (rows >=500*256 are pad)
    u16* vhT   = qh_bf + 8200192;       // 8,388,608 (chunk-tiled + swizzled)
    u16* w1T   = vhT + 8388608;         // 4,096
    u16* w2sw  = w1T + 4096;            // 32,768 (chunk-tiled + swizzled + log2e)
    u16* wqT   = w2sw + 32768;          // 65,536
    u16* wvT   = wqT + 65536;           // 65,536
    u16* fcwT  = wvT + 65536;           // 65,536
    u16* ctx   = fcwT + 65536;          // 8,192,000
    float* b2p = (float*)(qh_bf + 8195072);  // 512 floats inside qh_bf tail pad

    prep_kernel <<<dim3(64),     256, 0, stream>>>(wqs, wvs, fcw, w1, w2, b2,
                                                   wqT, wvT, fcwT, w1T, w2sw,
                                                   qh_bf, vhT, b2p);
    proj_kernel <<<dim3(500, 2), 512, 0, stream>>>(q, v, wqT, wvT, qh_bf, vhT);
    attn_kernel <<<dim3(256),    512, 0, stream>>>(qh_bf, vhT, w1T, b1, w2sw, b2p, ctx);
    final_kernel<<<dim3(500),    512, 0, stream>>>(ctx, fcwT, q, lng, lnb, out);
}

// Round 11
// 83.638 us; speedup vs baseline: 1.4621x; 1.0321x over previous
//
#include <hip/hip_runtime.h>
#include <math.h>

#define B_   64
#define L_   500
#define F_   256
#define H_   4
#define DK   64
#define LOG2E 1.44269504088896340736f

typedef unsigned short u16;
typedef unsigned int   u32;
typedef __attribute__((ext_vector_type(8))) short short8;
typedef __attribute__((ext_vector_type(4))) float f32x4;

static __device__ __forceinline__ u16 f2bf(float f) {
    u32 u = __float_as_uint(f);
    u32 r = (u + 0x7FFFu + ((u >> 16) & 1u)) >> 16;
    return (u16)r;
}
// pack two floats to 2x bf16 (round-half-up) in one u32: {hi=y, lo=x}
static __device__ __forceinline__ u32 pk_bf16_up(float x, float y) {
    u32 xb = __float_as_uint(x) + 0x8000u;
    u32 yb = __float_as_uint(y) + 0x8000u;
    return (xb >> 16) | (yb & 0xFFFF0000u);
}
static __device__ __forceinline__ float exp2_fast(float x) {
#if __has_builtin(__builtin_amdgcn_exp2f)
    return __builtin_amdgcn_exp2f(x);
#else
    return exp2f(x);
#endif
}

typedef __attribute__((address_space(3))) u32 lds32;
typedef const __attribute__((address_space(1))) u32 gbl32;
// async global->LDS DMA, 16 B/lane, LDS dest = uniform base + lane*16
static __device__ __forceinline__ void gload_lds16(const u16* g, u16* l) {
    __builtin_amdgcn_global_load_lds((gbl32*)g, (lds32*)l, 16, 0, 0);
}

// ---------------------------------------------------------------------------
// Prep: bf16 transposed weights + padded b2 + pad-zeroing of ws regions.
//  wqT/wvT/fcwT [256][256] ([n][k]); w1T[64][64]
//  w2sw: chunk-tiled + XOR-swizzled + PRE-SCALED by log2(e):
//        w2sw[cc][row][k] = log2e * w2[k ^ ((row&7)<<3)][cc*64+row]
//  b2p[512] float = log2e * b2 (tail -1e30 -> exp2() == 0)
// ---------------------------------------------------------------------------
__global__ __launch_bounds__(256) void prep_kernel(
    const float* __restrict__ wq, const float* __restrict__ wv,
    const float* __restrict__ fcw, const float* __restrict__ w1,
    const float* __restrict__ w2, const float* __restrict__ b2,
    u16* __restrict__ wqT, u16* __restrict__ wvT, u16* __restrict__ fcwT,
    u16* __restrict__ w1T, u16* __restrict__ w2sw,
    u16* __restrict__ qh_bf, u16* __restrict__ vhT, float* __restrict__ b2p)
{
    int t = blockIdx.x * 256 + threadIdx.x;
    int stride = gridDim.x * 256;                 // 16384
    for (int i = t; i < 256 * 256; i += stride) {
        int n = i >> 8, k = i & 255;
        wqT[i]  = f2bf(wq[k * 256 + n]);
        wvT[i]  = f2bf(wv[k * 256 + n]);
        fcwT[i] = f2bf(fcw[k * 256 + n]);
    }
    for (int i = t; i < 64 * 64; i += stride) {
        int n = i >> 6, k = i & 63;
        w1T[i] = f2bf(w1[k * 64 + n]);
    }
    // w2 chunk-tiled + swizzled + log2e-scaled
    for (int i = t; i < 512 * 64; i += stride) {
        int cc  = i >> 12;
        int row = (i >> 6) & 63;
        int kc  = i & 63;
        int n   = cc * 64 + row;
        int kl  = kc ^ ((row & 7) << 3);
        w2sw[i] = f2bf((n < 500 ? w2[kl * 500 + n] : 0.f) * LOG2E);
    }
    // padded, scaled bias (tail -> exp2() == 0)
    for (int i = t; i < 512; i += stride)
        b2p[i] = (i < 500) ? b2[i] * LOG2E : -1e30f;
    // zero qh_bf pad rows read by attn (rows >= 128000); b2p lives at 8195072+
    for (int i = t; i < 3072; i += stride)
        qh_bf[8192000 + i] = 0;
    // zero vhT swizzled pad slots: chunk 7, k 52..63 for every (bh, d)
    for (int i = t; i < 196608; i += stride) {
        int bh = i / 768;
        int r  = i - bh * 768;
        int d  = r / 12;
        int kk = 52 + (r - d * 12);
        vhT[((size_t)((bh * 8 + 7) * 64 + d)) * 64 + (kk ^ ((d & 7) << 3))] = 0;
    }
}

// ---------------------------------------------------------------------------
// Kernel 1: head projections, bf16 MFMA.
// grid (500, 2), block 512 = 8 waves in 2x4; block tile 64 rows x 256 cols.
// which=0: qh_bf [bh][500][64]
// which=1: vhT chunk-tiled+swizzled [bh][cc=8][d=64][k=64],
//          vhT[bh][cc][d][k ^ ((d&7)<<3)] = v_head[bh][d][cc*64+k]
// ---------------------------------------------------------------------------
__global__ __launch_bounds__(512) void proj_kernel(
    const float* __restrict__ q, const float* __restrict__ v,
    const u16* __restrict__ wqT, const u16* __restrict__ wvT,
    u16* __restrict__ qh_bf, u16* __restrict__ vhT)
{
    const int which = blockIdx.y;
    const float* __restrict__ x = which ? v : q;
    const u16*   __restrict__ wT = which ? wvT : wqT;

    __shared__ u16 Xs[64][72];    // [m][k], pad 144 B
    __shared__ u16 Ws[256][72];   // [n][k], pad 144 B

    const int tid  = threadIdx.x;
    const int wvid = tid >> 6, ln = tid & 63;
    const int n16  = ln & 15, quad = ln >> 4;
    const int wr   = wvid >> 2, wc = wvid & 3;   // 2 x 4
    const int row0 = blockIdx.x * 64;

    f32x4 acc[2][4];
    #pragma unroll
    for (int mt = 0; mt < 2; mt++)
        #pragma unroll
        for (int nt = 0; nt < 4; nt++) acc[mt][nt] = (f32x4){0.f, 0.f, 0.f, 0.f};

    for (int kc = 0; kc < 256; kc += 64) {
        // stage X (fp32 -> bf16): 64 x 64
        #pragma unroll
        for (int j = 0; j < 2; j++) {
            int idx = tid + 512 * j;
            int m = idx >> 4, k4 = idx & 15;
            float4 a = *(const float4*)&x[(size_t)(row0 + m) * 256 + kc + k4 * 4];
            __align__(8) u16 t4[4] = {f2bf(a.x), f2bf(a.y), f2bf(a.z), f2bf(a.w)};
            *(uint2*)&Xs[m][k4 * 4] = *(const uint2*)t4;
        }
        // stage W^T: 256 x 64 bf16
        #pragma unroll
        for (int j = 0; j < 4; j++) {
            int idx = tid + 512 * j;
            int n = idx >> 3, k8 = idx & 7;
            *(uint4*)&Ws[n][k8 * 8] = *(const uint4*)&wT[n * 256 + kc + k8 * 8];
        }
        __syncthreads();
        #pragma unroll
        for (int ks = 0; ks < 2; ks++) {
            short8 af[2], bfr[4];
            #pragma unroll
            for (int mt = 0; mt < 2; mt++)
                af[mt] = *(const short8*)&Xs[wr * 32 + mt * 16 + n16][ks * 32 + quad * 8];
            #pragma unroll
            for (int nt = 0; nt < 4; nt++)
                bfr[nt] = *(const short8*)&Ws[wc * 64 + nt * 16 + n16][ks * 32 + quad * 8];
            #pragma unroll
            for (int mt = 0; mt < 2; mt++)
                #pragma unroll
                for (int nt = 0; nt < 4; nt++)
                    acc[mt][nt] = __builtin_amdgcn_mfma_f32_16x16x32_bf16(
                        af[mt], bfr[nt], acc[mt][nt], 0, 0, 0);
        }
        __syncthreads();
    }

    // h = wc (64-col groups), d = nt*16 + n16
    if (which == 0) {
        #pragma unroll
        for (int mt = 0; mt < 2; mt++) {
            int m0 = row0 + wr * 32 + mt * 16 + quad * 4;   // mult of 4
            int b  = m0 / 500;
            int l0 = m0 - 500 * b;                           // group never straddles b
            #pragma unroll
            for (int nt = 0; nt < 4; nt++) {
                int d = nt * 16 + n16;
                u16* dst = qh_bf + ((size_t)((b * 4 + wc) * 500 + l0)) * 64 + d;
                #pragma unroll
                for (int i = 0; i < 4; i++)
                    dst[(size_t)i * 64] = f2bf(acc[mt][nt][i]);
            }
        }
    } else {
        #pragma unroll
        for (int mt = 0; mt < 2; mt++) {
            int m0 = row0 + wr * 32 + mt * 16 + quad * 4;
            int b  = m0 / 500;
            int l0 = m0 - 500 * b;                           // 4-aligned
            int cc = l0 >> 6, kk = l0 & 63;
            #pragma unroll
            for (int nt = 0; nt < 4; nt++) {
                int d = nt * 16 + n16;
                __align__(8) u16 t4[4];
                #pragma unroll
                for (int i = 0; i < 4; i++) t4[i] = f2bf(acc[mt][nt][i]);
                size_t base = ((size_t)(((b * 4 + wc) * 8 + cc) * 64 + d)) * 64;
                *(uint2*)&vhT[base + (kk ^ ((d & 7) << 3))] = *(const uint2*)t4;
            }
        }
    }
}

// ---------------------------------------------------------------------------
// Kernel 2: dense-synthesizer attention — LDS-bandwidth-optimized, 1 pass.
// grid (256) = 1 block/bh/CU; block 512 = 8 waves x 64 rows (4 rgs of 16).
// vs R10 (2 rgs, 2 rh passes, attn ~38us): B-fragments (w2, V, bias) feed
// FOUR MFMAs per read; chunk-steps halve (16 -> 8); barriers halve; Phase A
// and epilogue run once.  LDS-cycle floor ~11.5us; more per-step ILP for the
// 2-waves/SIMD schedule.  Live regs ~140 -> fine under (512,1)'s 256 budget.
// LDS: w2 64KB + V dbuf 16KB + b2 2KB + scr 72KB = 157.7KB (1 block/CU).
// ---------------------------------------------------------------------------
__global__ __launch_bounds__(512, 1) void attn_kernel(
    const u16* __restrict__ qh, const u16* __restrict__ vhT,
    const u16* __restrict__ w1T, const float* __restrict__ b1,
    const u16* __restrict__ w2sw, const float* __restrict__ b2p,
    u16* __restrict__ ctx)
{
    __shared__ __align__(16) u16 w2all[32768];       // [cc][row][k^swz], 64KB
    __shared__ __align__(16) u16 v_s[2][4096];       // [buf][d*64 + k^swz], 16KB
    __shared__ __align__(16) float b2s[512];         // scaled bias, 2KB
    __shared__ __align__(16) u16 scr[8][4][16][72];  // per-wave/rg s,P scratch

    const int tid  = threadIdx.x;
    const int wv   = tid >> 6;       // 0..7
    const int ln   = tid & 63;
    const int n16  = ln & 15;
    const int quad = ln >> 4;
    const int bh   = blockIdx.x;
    const int r0   = wv * 64;        // wave's 64 rows

    const u16* vg = vhT + (size_t)bh * 32768;

    // ---- one-shot staging: all of w2 (8 DMA/wave), v[0], b2 ----
    {
        int base = wv * 4096;
        #pragma unroll
        for (int j = 0; j < 8; j++)
            gload_lds16(w2sw + base + j * 512 + ln * 8, &w2all[base + j * 512]);
        gload_lds16(vg + wv * 512 + ln * 8, &v_s[0][wv * 512]);
        if (wv < 2)
            gload_lds16((const u16*)b2p + wv * 512 + ln * 8, (u16*)&b2s[wv * 256]);
    }

    const int b = bh >> 2, h = bh & 3;

    // ---- Phase A (swapped): s = relu(qh @ w1 + b1) -> packed scr, 4 rgs ----
    {
        short8 a0[4], a1[4];
        #pragma unroll
        for (int rg = 0; rg < 4; rg++) {
            const u16* qbase =
                qh + ((size_t)(bh * 500 + r0 + rg * 16 + n16)) * 64;
            a0[rg] = *(const short8*)(qbase + quad * 8);
            a1[rg] = *(const short8*)(qbase + 32 + quad * 8);
        }
        #pragma unroll
        for (int nt = 0; nt < 4; nt++) {
            const u16* wb = w1T + (nt * 16 + n16) * 64;
            short8 wA0 = *(const short8*)(wb + quad * 8);
            short8 wA1 = *(const short8*)(wb + 32 + quad * 8);
            float4 bv = *(const float4*)&b1[nt * 16 + quad * 4];
            #pragma unroll
            for (int rg = 0; rg < 4; rg++) {
                f32x4 c = {bv.x, bv.y, bv.z, bv.w};
                c = __builtin_amdgcn_mfma_f32_16x16x32_bf16(wA0, a0[rg], c, 0, 0, 0);
                c = __builtin_amdgcn_mfma_f32_16x16x32_bf16(wA1, a1[rg], c, 0, 0, 0);
                u32 p01 = pk_bf16_up(fmaxf(c[0], 0.f), fmaxf(c[1], 0.f));
                u32 p23 = pk_bf16_up(fmaxf(c[2], 0.f), fmaxf(c[3], 0.f));
                *(uint2*)&scr[wv][rg][n16][nt * 16 + quad * 4] =
                    make_uint2(p01, p23);
            }
        }
    }
    short8 sa0[4], sa1[4];
    #pragma unroll
    for (int rg = 0; rg < 4; rg++) {
        sa0[rg] = *(const short8*)&scr[wv][rg][n16][quad * 8];
        sa1[rg] = *(const short8*)&scr[wv][rg][n16][32 + quad * 8];
    }

    f32x4 oacc[4][4];
    #pragma unroll
    for (int rg = 0; rg < 4; rg++)
        #pragma unroll
        for (int nt = 0; nt < 4; nt++)
            oacc[rg][nt] = (f32x4){0.f, 0.f, 0.f, 0.f};
    float sm[4] = {0.f, 0.f, 0.f, 0.f};

    __syncthreads();   // prologue staging complete

    // ---- main: 8 chunks; B-frags shared across 4 rgs ----
    #pragma unroll 2
    for (int cc = 0; cc < 8; cc++) {
        if (cc < 7)
            gload_lds16(vg + (cc + 1) * 4096 + wv * 512 + ln * 8,
                        &v_s[(cc + 1) & 1][wv * 512]);
        const u16* vbuf = &v_s[cc & 1][0];

        // logits (swapped) + exp2 + pack -> scr, per t-tile
        #pragma unroll
        for (int t = 0; t < 4; t++) {
            int r  = t * 16 + n16;
            int sw = (r & 7) << 3;
            const u16* wb = &w2all[cc * 4096 + r * 64];
            short8 wA0 = *(const short8*)&wb[(quad * 8) ^ sw];
            short8 wA1 = *(const short8*)&wb[(32 + quad * 8) ^ sw];
            float4 bv = *(const float4*)&b2s[cc * 64 + t * 16 + quad * 4];
            #pragma unroll
            for (int rg = 0; rg < 4; rg++) {
                f32x4 c = {bv.x, bv.y, bv.z, bv.w};
                c = __builtin_amdgcn_mfma_f32_16x16x32_bf16(wA0, sa0[rg], c, 0, 0, 0);
                c = __builtin_amdgcn_mfma_f32_16x16x32_bf16(wA1, sa1[rg], c, 0, 0, 0);
                float e0 = exp2_fast(c[0]);
                float e1 = exp2_fast(c[1]);
                float e2 = exp2_fast(c[2]);
                float e3 = exp2_fast(c[3]);
                sm[rg] += (e0 + e1) + (e2 + e3);
                *(uint2*)&scr[wv][rg][n16][t * 16 + quad * 4] =
                    make_uint2(pk_bf16_up(e0, e1), pk_bf16_up(e2, e3));
            }
        }
        // PV: V-frag read once, feeds all 4 rgs
        #pragma unroll
        for (int ks = 0; ks < 2; ks++) {
            short8 pa[4];
            #pragma unroll
            for (int rg = 0; rg < 4; rg++)
                pa[rg] = *(const short8*)&scr[wv][rg][n16][ks * 32 + quad * 8];
            #pragma unroll
            for (int nt = 0; nt < 4; nt++) {
                int d   = nt * 16 + n16;
                int swd = (d & 7) << 3;
                short8 vb = *(const short8*)&vbuf[d * 64 +
                                                  ((ks * 32 + quad * 8) ^ swd)];
                #pragma unroll
                for (int rg = 0; rg < 4; rg++)
                    oacc[rg][nt] = __builtin_amdgcn_mfma_f32_16x16x32_bf16(
                        pa[rg], vb, oacc[rg][nt], 0, 0, 0);
            }
        }
        __syncthreads();   // next V staged; buffer safe to flip
    }

    // ---- epilogue: row-sum reduce + scaled bf16 store ----
    #pragma unroll
    for (int rg = 0; rg < 4; rg++) {
        float smt = sm[rg];
        smt += __shfl_xor(smt, 16);
        smt += __shfl_xor(smt, 32);   // lane now holds total for row n16
        #pragma unroll
        for (int i = 0; i < 4; i++) {
            int lrow = r0 + rg * 16 + quad * 4 + i;
            float si = __shfl(smt, quad * 4 + i);   // row (quad*4+i)'s sum
            if (lrow < 500) {
                float s = 1.f / si;
                u16* dst = &ctx[((size_t)(b * 500 + lrow)) * 256 + h * 64];
                #pragma unroll
                for (int nt = 0; nt < 4; nt++)
                    dst[nt * 16 + n16] = f2bf(oacc[rg][nt][i] * s);
            }
        }
    }
}

// ---------------------------------------------------------------------------
// Kernel 3: out = LayerNorm(ctx @ fc_w + q), bf16 MFMA + fused LN epilogue.
// grid (500), block 512 = 8 waves in 2x4; block tile 64 rows x 256 cols.
// ---------------------------------------------------------------------------
__global__ __launch_bounds__(512) void final_kernel(
    const u16* __restrict__ ctx, const u16* __restrict__ fcwT,
    const float* __restrict__ qres, const float* __restrict__ g,
    const float* __restrict__ bta, float* __restrict__ out)
{
    __shared__ u16 Xs[64][72];
    __shared__ u16 Ws[256][72];
    __shared__ float red[4][2][64];   // [wc][s1|s2][row]
    __shared__ float murs[2][64];     // [mu|rs][row]

    const int tid  = threadIdx.x;
    const int wvid = tid >> 6, ln = tid & 63;
    const int n16  = ln & 15, quad = ln >> 4;
    const int wr   = wvid >> 2, wc = wvid & 3;   // 2 x 4
    const int row0 = blockIdx.x * 64;

    f32x4 acc[2][4];
    #pragma unroll
    for (int mt = 0; mt < 2; mt++)
        #pragma unroll
        for (int nt = 0; nt < 4; nt++) acc[mt][nt] = (f32x4){0.f, 0.f, 0.f, 0.f};

    for (int kc = 0; kc < 256; kc += 64) {
        // stage X: 64 x 64 bf16
        {
            int idx = tid;
            int m = idx >> 3, k8 = idx & 7;
            *(uint4*)&Xs[m][k8 * 8] =
                *(const uint4*)&ctx[(size_t)(row0 + m) * 256 + kc + k8 * 8];
        }
        // stage W^T: 256 x 64 bf16
        #pragma unroll
        for (int j = 0; j < 4; j++) {
            int idx = tid + 512 * j;
            int n = idx >> 3, k8 = idx & 7;
            *(uint4*)&Ws[n][k8 * 8] = *(const uint4*)&fcwT[n * 256 + kc + k8 * 8];
        }
        __syncthreads();
        #pragma unroll
        for (int ks = 0; ks < 2; ks++) {
            short8 af[2], bfr[4];
            #pragma unroll
            for (int mt = 0; mt < 2; mt++)
                af[mt] = *(const short8*)&Xs[wr * 32 + mt * 16 + n16][ks * 32 + quad * 8];
            #pragma unroll
            for (int nt = 0; nt < 4; nt++)
                bfr[nt] = *(const short8*)&Ws[wc * 64 + nt * 16 + n16][ks * 32 + quad * 8];
            #pragma unroll
            for (int mt = 0; mt < 2; mt++)
                #pragma unroll
                for (int nt = 0; nt < 4; nt++)
                    acc[mt][nt] = __builtin_amdgcn_mfma_f32_16x16x32_bf16(
                        af[mt], bfr[nt], acc[mt][nt], 0, 0, 0);
        }
        __syncthreads();
    }

    // residual add
    #pragma unroll
    for (int mt = 0; mt < 2; mt++) {
        int m0 = row0 + wr * 32 + mt * 16 + quad * 4;
        #pragma unroll
        for (int i = 0; i < 4; i++) {
            const float* rp = &qres[(size_t)(m0 + i) * 256 + wc * 64 + n16];
            #pragma unroll
            for (int nt = 0; nt < 4; nt++)
                acc[mt][nt][i] += rp[nt * 16];
        }
    }
    // per-row partial sums -> LDS
    #pragma unroll
    for (int mt = 0; mt < 2; mt++) {
        #pragma unroll
        for (int i = 0; i < 4; i++) {
            float s1 = 0.f, s2 = 0.f;
            #pragma unroll
            for (int nt = 0; nt < 4; nt++) {
                float vv = acc[mt][nt][i];
                s1 += vv; s2 += vv * vv;
            }
            #pragma unroll
            for (int off = 1; off < 16; off <<= 1) {
                s1 += __shfl_xor(s1, off);
                s2 += __shfl_xor(s2, off);
            }
            if (n16 == 0) {
                int r = wr * 32 + mt * 16 + quad * 4 + i;
                red[wc][0][r] = s1;
                red[wc][1][r] = s2;
            }
        }
    }
    __syncthreads();
    if (tid < 64) {
        float S1 = red[0][0][tid] + red[1][0][tid] + red[2][0][tid] + red[3][0][tid];
        float S2 = red[0][1][tid] + red[1][1][tid] + red[2][1][tid] + red[3][1][tid];
        float mu  = S1 * 0.00390625f;
        float var = S2 * 0.00390625f - mu * mu;
        murs[0][tid] = mu;
        murs[1][tid] = rsqrtf(var + 1e-6f);
    }
    __syncthreads();

    float gv[4], bv[4];
    #pragma unroll
    for (int nt = 0; nt < 4; nt++) {
        int col = wc * 64 + nt * 16 + n16;
        gv[nt] = g[col];
        bv[nt] = bta[col];
    }
    #pragma unroll
    for (int mt = 0; mt < 2; mt++) {
        int rb = wr * 32 + mt * 16 + quad * 4;
        #pragma unroll
        for (int i = 0; i < 4; i++) {
            float mu = murs[0][rb + i];
            float rs = murs[1][rb + i];
            float* op = &out[(size_t)(row0 + rb + i) * 256 + wc * 64 + n16];
            #pragma unroll
            for (int nt = 0; nt < 4; nt++)
                op[nt * 16] = (acc[mt][nt][i] - mu) * rs * gv[nt] + bv[nt];
        }
    }
}

// ---------------------------------------------------------------------------
extern "C" void kernel_launch(void* const* d_in, const int* in_sizes, int n_in,
                              void* d_out, int out_size, void* d_ws, size_t ws_size,
                              hipStream_t stream)
{
    const float* q   = (const float*)d_in[0];
    const float* v   = (const float*)d_in[2];
    const float* wqs = (const float*)d_in[3];
    const float* wvs = (const float*)d_in[4];
    const float* w1  = (const float*)d_in[5];
    const float* b1  = (const float*)d_in[6];
    const float* w2  = (const float*)d_in[7];
    const float* b2  = (const float*)d_in[8];
    const float* fcw = (const float*)d_in[9];
    const float* lng = (const float*)d_in[10];
    const float* lnb = (const float*)d_in[11];
    float* out = (float*)d_out;

    u16* qh_bf = (u16*)d_ws;            // 8,200,192 (rows >=500*256 are pad)
    u16* vhT   = qh_bf + 8200192;       // 8,388,608 (chunk-tiled + swizzled)
    u16* w1T   = vhT + 8388608;         // 4,096
    u16* w2sw  = w1T + 4096;            // 32,768 (chunk-tiled + swizzled + log2e)
    u16* wqT   = w2sw + 32768;          // 65,536
    u16* wvT   = wqT + 65536;           // 65,536
    u16* fcwT  = wvT + 65536;           // 65,536
    u16* ctx   = fcwT + 65536;          // 8,192,000
    float* b2p = (float*)(qh_bf + 8195072);  // 512 floats inside qh_bf tail pad

    prep_kernel <<<dim3(64),     256, 0, stream>>>(wqs, wvs, fcw, w1, w2, b2,
                                                   wqT, wvT, fcwT, w1T, w2sw,
                                                   qh_bf, vhT, b2p);
    proj_kernel <<<dim3(500, 2), 512, 0, stream>>>(q, v, wqT, wvT, qh_bf, vhT);
    attn_kernel <<<dim3(256),    512, 0, stream>>>(qh_bf, vhT, w1T, b1, w2sw, b2p, ctx);
    final_kernel<<<dim3(500),    512, 0, stream>>>(ctx, fcwT, q, lng, lnb, out);
}